// Round 1
// baseline (1450.964 us; speedup 1.0000x reference)
//
#include <hip/hip_runtime.h>
#include <cstdint>
#include <cstddef>

#define B 64
#define PCH 512
#define O_CAPS 32
#define OD 16
#define IDC 8
#define I_CAPS 4096
#define ICHUNK 16
#define NPBLK 256  // I_CAPS / ICHUNK
#define Z 64
#define HDIM 1024

// workspace layout (in floats)
#define SZ_POSE (B * I_CAPS * IDC)                    // 2,097,152
#define OFF_POSE 0
#define OFF_BLOG (OFF_POSE + SZ_POSE)
#define SZ_BLOG ((size_t)B * I_CAPS * O_CAPS)         // 8,388,608
#define OFF_PART (OFF_BLOG + SZ_BLOG)
#define SZ_PART ((size_t)NPBLK * 2 * 32 * 512)        // 8,388,608
#define OFF_VBUF (OFF_PART + SZ_PART)
#define SZ_V (B * O_CAPS * OD)                        // 32,768
#define OFF_OUTC (OFF_VBUF + SZ_V)
#define OFF_H OFF_PART                                // reuse partials region for h

// ---------------------------------------------------------------------------
// K1: conv3x3 SAME + folded BN + ReLU + reshape + squash(k=8)  -> pose[b,i,k]
// block: (b, co-tile of 64). 256 threads = 64 px * 4 co-groups of 16.
// ---------------------------------------------------------------------------
__global__ __launch_bounds__(256) void conv_bn_squash(
    const float* __restrict__ x, const float* __restrict__ cw,
    const float* __restrict__ gamma, const float* __restrict__ beta,
    const float* __restrict__ mean, const float* __restrict__ var,
    float* __restrict__ pose) {
  __shared__ float lx[16 * 64];        // 4 KB: x[ci_chunk][px]
  __shared__ float lw[16 * 9 * 64];    // 36 KB: w[ci][tap][co]
  __shared__ float linv[64], lbias[64];
  const int b = blockIdx.x;
  const int co0 = blockIdx.y * 64;
  const int tid = threadIdx.x;
  if (tid < 64) {
    const int co = co0 + tid;
    const float iv = gamma[co] * rsqrtf(var[co] + 1e-5f);
    linv[tid] = iv;
    lbias[tid] = beta[co] - mean[co] * iv;
  }
  const int p = tid & 63, cg = tid >> 6;
  const int h = p >> 3, w = p & 7;
  float acc[16];
#pragma unroll
  for (int c = 0; c < 16; ++c) acc[c] = 0.f;
  __syncthreads();

  for (int ci0 = 0; ci0 < PCH; ci0 += 16) {
    __syncthreads();
    for (int idx = tid; idx < 1024; idx += 256)
      lx[idx] = x[((size_t)b * PCH + ci0 + (idx >> 6)) * 64 + (idx & 63)];
    for (int idx = tid; idx < 9216; idx += 256) {
      const int co = idx / 144, r = idx % 144, ci = r / 9, tp = r % 9;
      lw[(ci * 9 + tp) * 64 + co] =
          cw[((size_t)(co0 + co) * PCH + (ci0 + ci)) * 9 + tp] * linv[co];
    }
    __syncthreads();
    for (int ci = 0; ci < 16; ++ci) {
      float xv[9];
#pragma unroll
      for (int kh = 0; kh < 3; ++kh)
#pragma unroll
        for (int kw = 0; kw < 3; ++kw) {
          const int ih = h + kh - 1, iw = w + kw - 1;
          xv[kh * 3 + kw] = (ih >= 0 && ih < 8 && iw >= 0 && iw < 8)
                                ? lx[ci * 64 + ih * 8 + iw] : 0.f;
        }
#pragma unroll
      for (int t = 0; t < 9; ++t) {
        const float4* wq = (const float4*)&lw[(ci * 9 + t) * 64 + cg * 16];
#pragma unroll
        for (int q = 0; q < 4; ++q) {
          const float4 wv = wq[q];
          acc[q * 4 + 0] += wv.x * xv[t];
          acc[q * 4 + 1] += wv.y * xv[t];
          acc[q * 4 + 2] += wv.z * xv[t];
          acc[q * 4 + 3] += wv.w * xv[t];
        }
      }
    }
  }
  // epilogue: bias + relu + squash over each group of 8 channels
#pragma unroll
  for (int c = 0; c < 16; ++c) acc[c] = fmaxf(acc[c] + lbias[cg * 16 + c], 0.f);
#pragma unroll
  for (int g = 0; g < 2; ++g) {
    float ms = 0.f;
#pragma unroll
    for (int j = 0; j < 8; ++j) ms += acc[g * 8 + j] * acc[g * 8 + j];
    const float sc = ms / (1.f + ms) / (sqrtf(ms) + 1e-8f);
    const int cap = (co0 >> 3) + cg * 2 + g;
    float* dst = pose + ((size_t)b * I_CAPS + cap * 64 + p) * IDC;
#pragma unroll
    for (int j = 0; j < 8; ++j) dst[j] = acc[g * 8 + j] * sc;
  }
}

// ---------------------------------------------------------------------------
// Routing phase: recompute X[o,d] = sum_k W[o,i,d,k]*pose[b,i,k] per (b,i);
// MODE 0: c = 1/32 (iter 0).  MODE 1: logit = v0.X, store blog, softmax.
// MODE 2: logit = blog + v1.X, softmax.  Accumulate c*X into LDS acc[bl][d][o],
// write block partials. Wave layout: lane = o*2+dh (o<32, dh = d-half).
// block: (i-chunk of 16, b-half of 32). 512 threads = 8 waves, wave owns
// b ≡ wv (mod 8) rows -> no races, no inner barriers.
// ---------------------------------------------------------------------------
template <int MODE>
__global__ __launch_bounds__(512) void routing_phase(
    const float* __restrict__ pose, const float* __restrict__ capsw,
    const float* __restrict__ vbuf, float* __restrict__ blog,
    float* __restrict__ partials) {
  __shared__ float acc[32 * 512];  // 64 KB
  const int tid = threadIdx.x;
  const int lane = tid & 63;
  const int wv = tid >> 6;
  const int o = lane >> 1, dh = lane & 1;
  const int i0 = blockIdx.x * ICHUNK;
  const int b0 = blockIdx.y * 32;

  for (int t = tid; t < 32 * 512; t += 512) acc[t] = 0.f;
  __syncthreads();

  const float* wbase =
      capsw + (size_t)o * ((size_t)I_CAPS * OD * IDC) + (size_t)dh * 64;

  for (int ii = 0; ii < ICHUNK; ++ii) {
    const int i = i0 + ii;
    float wf[64];  // W[o][i][dh*8 + j][k], 64 contiguous floats
    const float4* wp = (const float4*)(wbase + (size_t)i * (OD * IDC));
#pragma unroll
    for (int q = 0; q < 16; ++q) {
      const float4 v4 = wp[q];
      wf[q * 4 + 0] = v4.x; wf[q * 4 + 1] = v4.y;
      wf[q * 4 + 2] = v4.z; wf[q * 4 + 3] = v4.w;
    }
    for (int bl = wv; bl < 32; bl += 8) {
      const int b = b0 + bl;
      const float4* pp = (const float4*)(pose + ((size_t)b * I_CAPS + i) * IDC);
      const float4 p0 = pp[0], p1 = pp[1];
      const float pk[8] = {p0.x, p0.y, p0.z, p0.w, p1.x, p1.y, p1.z, p1.w};
      float X[8];
#pragma unroll
      for (int j = 0; j < 8; ++j) {
        float s = 0.f;
#pragma unroll
        for (int k = 0; k < 8; ++k) s += wf[j * 8 + k] * pk[k];
        X[j] = s;
      }
      float c;
      if (MODE == 0) {
        c = 1.0f / 32.0f;
      } else {
        const float* vrow = vbuf + ((size_t)(b * O_CAPS + o) * OD) + dh * 8;
        float lg = 0.f;
#pragma unroll
        for (int j = 0; j < 8; ++j) lg += vrow[j] * X[j];
        lg += __shfl_xor(lg, 1, 64);  // both halves now hold full v.X over 16 d
        const size_t bidx = ((size_t)b * I_CAPS + i) * O_CAPS + o;
        if (MODE == 2) lg += blog[bidx];
        if (MODE == 1 && dh == 0) blog[bidx] = lg;
        float mx = lg;
#pragma unroll
        for (int s = 2; s < 64; s <<= 1) mx = fmaxf(mx, __shfl_xor(mx, s, 64));
        const float e = __expf(lg - mx);
        float sm = e;
#pragma unroll
        for (int s = 2; s < 64; s <<= 1) sm += __shfl_xor(sm, s, 64);
        c = e / sm;
      }
      // acc layout [bl][d][o]: 2-way-only LDS bank aliasing across the wave
      float* ab = acc + (bl * 512 + dh * 256 + o);
#pragma unroll
      for (int j = 0; j < 8; ++j) ab[j * 32] += c * X[j];
    }
  }
  __syncthreads();
  float* dst = partials + (size_t)(blockIdx.x * 2 + blockIdx.y) * (32 * 512);
  for (int t = tid; t < 32 * 512; t += 512) dst[t] = acc[t];
}

// ---------------------------------------------------------------------------
// Reduce partials over the 256 i-chunks, then squash over d (16) -> dst[b,o,d]
// ---------------------------------------------------------------------------
__global__ __launch_bounds__(256) void reduce_squash(
    const float* __restrict__ partials, float* __restrict__ dst) {
  const int t = blockIdx.x * 256 + threadIdx.x;  // 0..32767 -> (b,o,d)
  const int b = t >> 9;
  const int r = t & 511;
  const int o = r >> 4, d = r & 15;
  const int bh = b >> 5, bl = b & 31;
  const size_t elem = (size_t)bl * 512 + (size_t)d * 32 + o;
  float s = 0.f;
  for (int blk = 0; blk < NPBLK; ++blk)
    s += partials[(size_t)(blk * 2 + bh) * (32 * 512) + elem];
  float sq = s * s;
  sq += __shfl_xor(sq, 1, 64);
  sq += __shfl_xor(sq, 2, 64);
  sq += __shfl_xor(sq, 4, 64);
  sq += __shfl_xor(sq, 8, 64);
  const float sc = sq / (1.f + sq) / (sqrtf(sq) + 1e-8f);
  dst[t] = s * sc;
}

// ---------------------------------------------------------------------------
// VAE head
// ---------------------------------------------------------------------------
__global__ __launch_bounds__(256) void fc1_relu(
    const float* __restrict__ outc, const float* __restrict__ w1,
    const float* __restrict__ b1, float* __restrict__ h) {
  const int gid = blockIdx.x * 256 + threadIdx.x;  // < 2048*1024
  const int n = gid >> 10, j = gid & 1023;
  float s = b1[j];
#pragma unroll
  for (int k = 0; k < 16; ++k) s += outc[n * 16 + k] * w1[k * 1024 + j];
  h[gid] = fmaxf(s, 0.f);
}

__global__ __launch_bounds__(256) void fc2_mu(
    const float* __restrict__ h, const float* __restrict__ w2,
    const float* __restrict__ b2, float* __restrict__ dout) {
  __shared__ float lh[4 * 1024];
  const int tid = threadIdx.x;
  const int nl = tid >> 6, m = tid & 63;
  const int n0 = blockIdx.x * 4;
  for (int idx = tid; idx < 4096; idx += 256)
    lh[idx] = h[(size_t)n0 * 1024 + idx];
  __syncthreads();
  float s = b2[m];
  const float* hr = lh + nl * 1024;
#pragma unroll 8
  for (int j = 0; j < 1024; ++j) s += hr[j] * w2[j * 64 + m];
  const int n = n0 + nl;
  dout[n * 64 + m] = s;            // z
  dout[131072 + n * 64 + m] = s;   // z_mu
}

__global__ __launch_bounds__(256) void fc_var(
    const float* __restrict__ outc, const float* __restrict__ wv,
    const float* __restrict__ bv, float* __restrict__ dout) {
  const int gid = blockIdx.x * 256 + threadIdx.x;  // < 131072
  const int n = gid >> 6, m = gid & 63;
  float s = bv[m];
#pragma unroll
  for (int k = 0; k < 16; ++k) s += outc[n * 16 + k] * wv[k * 64 + m];
  const float sp = (s > 0.f) ? (s + log1pf(__expf(-s))) : log1pf(__expf(s));
  dout[262144 + gid] = sp + 1e-8f;
}

// ---------------------------------------------------------------------------
extern "C" void kernel_launch(void* const* d_in, const int* in_sizes, int n_in,
                              void* d_out, int out_size, void* d_ws,
                              size_t ws_size, hipStream_t stream) {
  const float* x = (const float*)d_in[0];
  const float* conv_w = (const float*)d_in[1];
  const float* bn_gamma = (const float*)d_in[2];
  const float* bn_beta = (const float*)d_in[3];
  const float* bn_mean = (const float*)d_in[4];
  const float* bn_var = (const float*)d_in[5];
  const float* caps_w = (const float*)d_in[6];
  const float* fcm_w1 = (const float*)d_in[7];
  const float* fcm_b1 = (const float*)d_in[8];
  const float* fcm_w2 = (const float*)d_in[9];
  const float* fcm_b2 = (const float*)d_in[10];
  const float* fcv_w = (const float*)d_in[11];
  const float* fcv_b = (const float*)d_in[12];
  float* out = (float*)d_out;
  float* ws = (float*)d_ws;

  float* pose = ws + OFF_POSE;
  float* blog = ws + OFF_BLOG;
  float* part = ws + OFF_PART;
  float* vbuf = ws + OFF_VBUF;
  float* outc = ws + OFF_OUTC;
  float* h = ws + OFF_H;

  conv_bn_squash<<<dim3(64, 8), 256, 0, stream>>>(
      x, conv_w, bn_gamma, bn_beta, bn_mean, bn_var, pose);

  routing_phase<0><<<dim3(NPBLK, 2), 512, 0, stream>>>(
      pose, caps_w, nullptr, nullptr, part);
  reduce_squash<<<128, 256, 0, stream>>>(part, vbuf);

  routing_phase<1><<<dim3(NPBLK, 2), 512, 0, stream>>>(
      pose, caps_w, vbuf, blog, part);
  reduce_squash<<<128, 256, 0, stream>>>(part, vbuf);

  routing_phase<2><<<dim3(NPBLK, 2), 512, 0, stream>>>(
      pose, caps_w, vbuf, blog, part);
  reduce_squash<<<128, 256, 0, stream>>>(part, outc);

  fc1_relu<<<8192, 256, 0, stream>>>(outc, fcm_w1, fcm_b1, h);
  fc2_mu<<<512, 256, 0, stream>>>(h, fcm_w2, fcm_b2, out);
  fc_var<<<512, 256, 0, stream>>>(outc, fcv_w, fcv_b, out);
}